// Round 14
// baseline (989.424 us; speedup 1.0000x reference)
//
#include <hip/hip_runtime.h>
#include <math.h>

#define N_MEM 100
#define C_DIM 768
#define HW_SZ 2304            // 48*48
#define TEMP 0.07f
#define EPS_F 1e-8f
#define LAM_F 0.01f           // 1/N_MEM
#define NORM_EPS 1e-12f

#define NS   4                // n-split stripes in mTp layout (fixed)
#define SW   25               // stripe width (N_MEM/NS)
#define SWP  28               // padded stripe (112B: 16B-aligned stripes)
#define CROW (NS * SWP)       // 112 floats per c in mTp
#define ROWS 64               // rows per block
#define SCP  101              // LDS row pad: lane*101%32=lane*5 -> 2-way max
#define ZB   12               // scores c-loop batch (R14: 8->12, covers z lat)
#define CB_R 8                // recon c-tile per stage per wave

typedef float f32x2 __attribute__((ext_vector_type(2)));
typedef float f32x4 __attribute__((ext_vector_type(4)));

// -------------------------------------------------------------------------
// Kernel 1: L2-normalize memory rows, store PADDED-TRANSPOSED:
// mTp[c][ns][SWP]. Same value bits as R1's mT (same reduction).
// -------------------------------------------------------------------------
__global__ __launch_bounds__(64) void prep_mT(const float* __restrict__ mem,
                                              float* __restrict__ mTp) {
#pragma clang fp contract(off)
    const int n = blockIdx.x;        // 0..99
    const int lane = threadIdx.x;    // 0..63
    const float* row = mem + n * C_DIM;

    float ss = 0.f;
    for (int c = lane; c < C_DIM; c += 64) {
        float v = row[c];
        ss = fmaf(v, v, ss);
    }
    for (int off = 32; off > 0; off >>= 1)
        ss += __shfl_down(ss, off);
    float norm = sqrtf(__shfl(ss, 0));
    float inv = 1.0f / fmaxf(norm, NORM_EPS);

    const int nsI = n / SW, j = n % SW;
    for (int c = lane; c < C_DIM; c += 64)
        mTp[(size_t)c * CROW + nsI * SWP + j] = row[c] * inv;
}

// -------------------------------------------------------------------------
// FUSED kernel: scores -> softmax -> shrinkage -> w_hat -> reconstruction.
//
// R14 changes vs R13 (both order-preserving, bit-identical):
//  * ZB 8 -> 12: with pk_fma the per-batch issue time (~208cy) no longer
//    covers ~900cy HBM z-latency at 4 waves/SIMD; 12 does (1248cy).
//  * Recon: wh stripes nc=0,1 hoisted into registers ONCE (50 floats as
//    f32x2) after the wh-write sync; nc=2,3 still read from LDS per cb.
//    Halves the 2400 per-thread wr ds_reads. VGPR stays < 128 (the
//    4-waves/SIMD cliff); a full 100-float hoist would cross it.
// v2/vs accumulation order (nc 0..3, q ascending, then +vs) unchanged.
// LDS: sc 25856B + mbuf 14336B = 40192B -> 4 blocks/CU.
// -------------------------------------------------------------------------
__global__ __launch_bounds__(256) void memmod_fused(const float* __restrict__ F,
                                                    const float* __restrict__ mTp,
                                                    float* __restrict__ Fhat,
                                                    float* __restrict__ What) {
#pragma clang fp contract(off)
    __shared__ float sc[ROWS][SCP];              // scores, then w_hat
    __shared__ float mbuf[NS * CB_R * CROW];     // recon m chunk

    const int tid  = threadIdx.x;
    const int lane = tid & 63;
    const int ws   = tid >> 6;
    const int wsu  = __builtin_amdgcn_readfirstlane(ws);   // force SGPR addr
    const int blk  = blockIdx.x;                 // 0..2303
    const int b    = blk / 36;                   // 36 blocks per image
    const int hw   = (blk % 36) * 64 + lane;     // 0..2303
    const int rowg = b * HW_SZ + hw;             // global row id
    const size_t plane = (size_t)b * C_DIM * HW_SZ + hw;

    f32x2 acc2[12];                              // chains j=0..23, paired
    float acc24 = 0.f;                           // chain j=24
#pragma unroll
    for (int p = 0; p < 12; ++p) acc2[p] = f32x2{0.f, 0.f};
    float ss = 0.f;

    // ---- scores: batched z loads, sequential-c PK-FMA chains, s_load m ----
    const float* Fp = F + plane;
    for (int c0 = 0; c0 < C_DIM; c0 += ZB) {
        float zb[ZB];                            // static indices -> VGPRs
#pragma unroll
        for (int u = 0; u < ZB; ++u)
            zb[u] = Fp[(size_t)(c0 + u) * HW_SZ];    // 12 coalesced loads in flight
#pragma unroll
        for (int u = 0; u < ZB; ++u) {
            const float zc = zb[u];
            ss = fmaf(zc, zc, ss);
            const float* mch = mTp + (size_t)(c0 + u) * CROW + wsu * SWP;  // s_load
            const f32x4* mch4 = reinterpret_cast<const f32x4*>(mch);       // 16B-aligned
            f32x2 zz; zz.x = zc; zz.y = zc;
#pragma unroll
            for (int q = 0; q < 6; ++q) {
                const f32x4 m4 = mch4[q];
                const f32x2 mlo = __builtin_shufflevector(m4, m4, 0, 1);
                const f32x2 mhi = __builtin_shufflevector(m4, m4, 2, 3);
                acc2[2 * q]     = __builtin_elementwise_fma(zz, mlo, acc2[2 * q]);
                acc2[2 * q + 1] = __builtin_elementwise_fma(zz, mhi, acc2[2 * q + 1]);
            }
            acc24 = fmaf(zc, mch[24], acc24);
        }
    }

    // ---- unpack to the R11 acc[] layout (bit-identical values) ----
    float acc[SW];
#pragma unroll
    for (int p = 0; p < 12; ++p) { acc[2 * p] = acc2[p].x; acc[2 * p + 1] = acc2[p].y; }
    acc[24] = acc24;

    // ---- stage scores to LDS (read-only during softmax scans) ----
#pragma unroll
    for (int j = 0; j < SW; ++j)
        sc[lane][wsu * SW + j] = acc[j];
    __syncthreads();

    // ---- softmax + shrinkage: R1's exact op sequence, n = 0..99 ----
    const float scale = 1.0f / (fmaxf(sqrtf(ss), NORM_EPS) * TEMP);
    float mx = -INFINITY;
    for (int n = 0; n < N_MEM; ++n)
        mx = fmaxf(mx, sc[lane][n] * scale);
    float sum = 0.f;
    for (int n = 0; n < N_MEM; ++n)
        sum += expf(sc[lane][n] * scale - mx);
    float s2 = 0.f;
    for (int n = 0; n < N_MEM; ++n) {
        const float e = expf(sc[lane][n] * scale - mx);   // same bits as pass 2
        const float w = e / sum;
        const float d = w - LAM_F;
        s2 += (d > 0.f ? d : 0.f) * w / (fabsf(d) + EPS_F);
    }
    const float s2c = fmaxf(s2, EPS_F);

    // ---- all waves done reading scores; overwrite sc with w_hat ----
    __syncthreads();

    // own stripe: recompute wh from registers (same bits), emit to HBM + LDS
    float* wout = What + (size_t)rowg * N_MEM + wsu * SW;
#pragma unroll
    for (int j = 0; j < SW; ++j) {
        const float e = expf(acc[j] * scale - mx);
        const float w = e / sum;
        const float d = w - LAM_F;
        const float wh = (d > 0.f ? d : 0.f) * w / (fabsf(d) + EPS_F);
        const float whn = wh / s2c;
        wout[j] = whn;                           // output w_hat_spatial
        sc[lane][wsu * SW + j] = whn;            // recon operand (same bits)
    }

    // ---- wh visible to all waves; hoist stripes nc=0,1 to registers ----
    __syncthreads();
    f32x2 whA[12], whB[12];
    float whA24, whB24;
#pragma unroll
    for (int p = 0; p < 12; ++p) {
        whA[p] = f32x2{sc[lane][0 * SW + 2 * p], sc[lane][0 * SW + 2 * p + 1]};
        whB[p] = f32x2{sc[lane][1 * SW + 2 * p], sc[lane][1 * SW + 2 * p + 1]};
    }
    whA24 = sc[lane][0 * SW + 24];
    whB24 = sc[lane][1 * SW + 24];

    // ---- reconstruction: Fhat[b][c][hw] = sum_n wh[row][n]*m[n][c] ----
    float* Fo = Fhat + plane;
    const int c0w = wsu * (C_DIM / NS);          // 192-wide c-stripe

    for (int cb = 0; cb < C_DIM / NS; cb += CB_R) {
        __syncthreads();                         // prior mbuf chunk consumed
        {   // stage 4 c-regions x CB_R c's x 112 floats = 896 float4
            float4* dst4 = reinterpret_cast<float4*>(mbuf);
            for (int i = tid; i < NS * CB_R * CROW / 4; i += 256) {
                const int s   = i / (CB_R * CROW / 4);
                const int rem = i % (CB_R * CROW / 4);
                const float4* src4 = reinterpret_cast<const float4*>(
                    mTp + (size_t)(s * (C_DIM / NS) + cb) * CROW);
                dst4[i] = src4[rem];
            }
        }
        __syncthreads();

        f32x2 v2[CB_R];                          // even/odd-j partial chains
        float vs[CB_R];                          // j=24 chain
#pragma unroll
        for (int t = 0; t < CB_R; ++t) { v2[t] = f32x2{0.f, 0.f}; vs[t] = 0.f; }

        // ---- nc = 0: wh from registers (whA) ----
#pragma unroll
        for (int t = 0; t < CB_R; ++t) {
            const float* mch = mbuf + (wsu * CB_R + t) * CROW + 0 * SWP;
            const f32x4* mch4 = reinterpret_cast<const f32x4*>(mch);
#pragma unroll
            for (int q = 0; q < 6; ++q) {
                const f32x4 m4 = mch4[q];
                const f32x2 mlo = __builtin_shufflevector(m4, m4, 0, 1);
                const f32x2 mhi = __builtin_shufflevector(m4, m4, 2, 3);
                v2[t] = __builtin_elementwise_fma(whA[2 * q], mlo, v2[t]);
                v2[t] = __builtin_elementwise_fma(whA[2 * q + 1], mhi, v2[t]);
            }
            vs[t] = fmaf(whA24, mch[24], vs[t]);
        }
        // ---- nc = 1: wh from registers (whB) ----
#pragma unroll
        for (int t = 0; t < CB_R; ++t) {
            const float* mch = mbuf + (wsu * CB_R + t) * CROW + 1 * SWP;
            const f32x4* mch4 = reinterpret_cast<const f32x4*>(mch);
#pragma unroll
            for (int q = 0; q < 6; ++q) {
                const f32x4 m4 = mch4[q];
                const f32x2 mlo = __builtin_shufflevector(m4, m4, 0, 1);
                const f32x2 mhi = __builtin_shufflevector(m4, m4, 2, 3);
                v2[t] = __builtin_elementwise_fma(whB[2 * q], mlo, v2[t]);
                v2[t] = __builtin_elementwise_fma(whB[2 * q + 1], mhi, v2[t]);
            }
            vs[t] = fmaf(whB24, mch[24], vs[t]);
        }
        // ---- nc = 2,3: wh from LDS (as R13) ----
#pragma unroll
        for (int nc = 2; nc < NS; ++nc) {
            f32x2 wr2[12];
#pragma unroll
            for (int p = 0; p < 12; ++p)
                wr2[p] = f32x2{sc[lane][nc * SW + 2 * p],
                               sc[lane][nc * SW + 2 * p + 1]};   // 2-way max
            const float wr24 = sc[lane][nc * SW + 24];
#pragma unroll
            for (int t = 0; t < CB_R; ++t) {
                const float* mch = mbuf + (wsu * CB_R + t) * CROW + nc * SWP;
                const f32x4* mch4 = reinterpret_cast<const f32x4*>(mch);
#pragma unroll
                for (int q = 0; q < 6; ++q) {
                    const f32x4 m4 = mch4[q];
                    const f32x2 mlo = __builtin_shufflevector(m4, m4, 0, 1);
                    const f32x2 mhi = __builtin_shufflevector(m4, m4, 2, 3);
                    v2[t] = __builtin_elementwise_fma(wr2[2 * q], mlo, v2[t]);
                    v2[t] = __builtin_elementwise_fma(wr2[2 * q + 1], mhi, v2[t]);
                }
                vs[t] = fmaf(wr24, mch[24], vs[t]);
            }
        }
#pragma unroll
        for (int t = 0; t < CB_R; ++t)
            Fo[(size_t)(c0w + cb + t) * HW_SZ] = (v2[t].x + v2[t].y) + vs[t];
    }
}

// -------------------------------------------------------------------------
extern "C" void kernel_launch(void* const* d_in, const int* in_sizes, int n_in,
                              void* d_out, int out_size, void* d_ws, size_t ws_size,
                              hipStream_t stream) {
    const float* F   = (const float*)d_in[0];   // [64,768,48,48]
    const float* mem = (const float*)d_in[1];   // [100,768]
    float* Fhat = (float*)d_out;                               // 113,246,208 floats
    float* What = (float*)d_out + (size_t)64 * 768 * 48 * 48;  // 14,745,600 floats
    float* mTp  = (float*)d_ws;                                // 768*112 floats

    prep_mT<<<N_MEM, 64, 0, stream>>>(mem, mTp);
    memmod_fused<<<2304, 256, 0, stream>>>(F, mTp, Fhat, What);
}

// Round 15
// 967.446 us; speedup vs baseline: 1.0227x; 1.0227x over previous
//
#include <hip/hip_runtime.h>
#include <math.h>

#define N_MEM 100
#define C_DIM 768
#define HW_SZ 2304            // 48*48
#define TEMP 0.07f
#define EPS_F 1e-8f
#define LAM_F 0.01f           // 1/N_MEM
#define NORM_EPS 1e-12f

#define NS   4                // n-split stripes in mTp layout (fixed)
#define SW   25               // stripe width (N_MEM/NS)
#define SWP  28               // padded stripe (112B: 16B-aligned stripes)
#define CROW (NS * SWP)       // 112 floats per c in mTp
#define ROWS 64               // rows per block
#define SCP  101              // LDS row pad: lane*101%32=lane*5 -> 2-way max
#define ZB   8                // scores c-loop batch (R13 value)
#define CB_R 8                // recon c-tile per stage per wave

typedef float f32x2 __attribute__((ext_vector_type(2)));
typedef float f32x4 __attribute__((ext_vector_type(4)));

// -------------------------------------------------------------------------
// Kernel 1: L2-normalize memory rows, store PADDED-TRANSPOSED:
// mTp[c][ns][SWP]. Same value bits as R1's mT (same reduction).
// -------------------------------------------------------------------------
__global__ __launch_bounds__(64) void prep_mT(const float* __restrict__ mem,
                                              float* __restrict__ mTp) {
#pragma clang fp contract(off)
    const int n = blockIdx.x;        // 0..99
    const int lane = threadIdx.x;    // 0..63
    const float* row = mem + n * C_DIM;

    float ss = 0.f;
    for (int c = lane; c < C_DIM; c += 64) {
        float v = row[c];
        ss = fmaf(v, v, ss);
    }
    for (int off = 32; off > 0; off >>= 1)
        ss += __shfl_down(ss, off);
    float norm = sqrtf(__shfl(ss, 0));
    float inv = 1.0f / fmaxf(norm, NORM_EPS);

    const int nsI = n / SW, j = n % SW;
    for (int c = lane; c < C_DIM; c += 64)
        mTp[(size_t)c * CROW + nsI * SWP + j] = row[c] * inv;
}

// -------------------------------------------------------------------------
// FUSED kernel: scores -> softmax -> shrinkage -> w_hat -> reconstruction.
//
// R15 = R13 revert (R14's ZB=12 + wh-hoist both null/negative) + one
// scheduling nudge: the 7 m-loads per c are grouped into named registers
// BEFORE the 13 pk-FMAs (was load-use interleaved). Same addresses, same
// values, same chain order -> bit-identical (absmax exactly 0.004943848
// in every passing round; threshold 5.27e-3).
// LDS: sc 25856B + mbuf 14336B = 40192B -> 4 blocks/CU.
// -------------------------------------------------------------------------
__global__ __launch_bounds__(256) void memmod_fused(const float* __restrict__ F,
                                                    const float* __restrict__ mTp,
                                                    float* __restrict__ Fhat,
                                                    float* __restrict__ What) {
#pragma clang fp contract(off)
    __shared__ float sc[ROWS][SCP];              // scores, then w_hat
    __shared__ float mbuf[NS * CB_R * CROW];     // recon m chunk

    const int tid  = threadIdx.x;
    const int lane = tid & 63;
    const int ws   = tid >> 6;
    const int wsu  = __builtin_amdgcn_readfirstlane(ws);   // force SGPR addr
    const int blk  = blockIdx.x;                 // 0..2303
    const int b    = blk / 36;                   // 36 blocks per image
    const int hw   = (blk % 36) * 64 + lane;     // 0..2303
    const int rowg = b * HW_SZ + hw;             // global row id
    const size_t plane = (size_t)b * C_DIM * HW_SZ + hw;

    f32x2 acc2[12];                              // chains j=0..23, paired
    float acc24 = 0.f;                           // chain j=24
#pragma unroll
    for (int p = 0; p < 12; ++p) acc2[p] = f32x2{0.f, 0.f};
    float ss = 0.f;

    // ---- scores: batched z loads, sequential-c PK-FMA chains, s_load m ----
    const float* Fp = F + plane;
    for (int c0 = 0; c0 < C_DIM; c0 += ZB) {
        float zb[ZB];                            // static indices -> VGPRs
#pragma unroll
        for (int u = 0; u < ZB; ++u)
            zb[u] = Fp[(size_t)(c0 + u) * HW_SZ];    // 8 coalesced loads in flight
#pragma unroll
        for (int u = 0; u < ZB; ++u) {
            const float zc = zb[u];
            ss = fmaf(zc, zc, ss);
            const float* mch = mTp + (size_t)(c0 + u) * CROW + wsu * SWP;  // s_load
            const f32x4* mch4 = reinterpret_cast<const f32x4*>(mch);       // 16B-aligned

            // group ALL m loads for this c first (clean SMEM batch), ...
            const f32x4 m0 = mch4[0];
            const f32x4 m1 = mch4[1];
            const f32x4 m2 = mch4[2];
            const f32x4 m3 = mch4[3];
            const f32x4 m4 = mch4[4];
            const f32x4 m5 = mch4[5];
            const float m24 = mch[24];

            // ... then the 13 FMAs (chain order unchanged -> same bits)
            f32x2 zz; zz.x = zc; zz.y = zc;
            acc2[0]  = __builtin_elementwise_fma(zz, __builtin_shufflevector(m0, m0, 0, 1), acc2[0]);
            acc2[1]  = __builtin_elementwise_fma(zz, __builtin_shufflevector(m0, m0, 2, 3), acc2[1]);
            acc2[2]  = __builtin_elementwise_fma(zz, __builtin_shufflevector(m1, m1, 0, 1), acc2[2]);
            acc2[3]  = __builtin_elementwise_fma(zz, __builtin_shufflevector(m1, m1, 2, 3), acc2[3]);
            acc2[4]  = __builtin_elementwise_fma(zz, __builtin_shufflevector(m2, m2, 0, 1), acc2[4]);
            acc2[5]  = __builtin_elementwise_fma(zz, __builtin_shufflevector(m2, m2, 2, 3), acc2[5]);
            acc2[6]  = __builtin_elementwise_fma(zz, __builtin_shufflevector(m3, m3, 0, 1), acc2[6]);
            acc2[7]  = __builtin_elementwise_fma(zz, __builtin_shufflevector(m3, m3, 2, 3), acc2[7]);
            acc2[8]  = __builtin_elementwise_fma(zz, __builtin_shufflevector(m4, m4, 0, 1), acc2[8]);
            acc2[9]  = __builtin_elementwise_fma(zz, __builtin_shufflevector(m4, m4, 2, 3), acc2[9]);
            acc2[10] = __builtin_elementwise_fma(zz, __builtin_shufflevector(m5, m5, 0, 1), acc2[10]);
            acc2[11] = __builtin_elementwise_fma(zz, __builtin_shufflevector(m5, m5, 2, 3), acc2[11]);
            acc24 = fmaf(zc, m24, acc24);
        }
    }

    // ---- unpack to the R11 acc[] layout (bit-identical values) ----
    float acc[SW];
#pragma unroll
    for (int p = 0; p < 12; ++p) { acc[2 * p] = acc2[p].x; acc[2 * p + 1] = acc2[p].y; }
    acc[24] = acc24;

    // ---- stage scores to LDS (read-only during softmax scans) ----
#pragma unroll
    for (int j = 0; j < SW; ++j)
        sc[lane][wsu * SW + j] = acc[j];
    __syncthreads();

    // ---- softmax + shrinkage: R1's exact op sequence, n = 0..99 ----
    const float scale = 1.0f / (fmaxf(sqrtf(ss), NORM_EPS) * TEMP);
    float mx = -INFINITY;
    for (int n = 0; n < N_MEM; ++n)
        mx = fmaxf(mx, sc[lane][n] * scale);
    float sum = 0.f;
    for (int n = 0; n < N_MEM; ++n)
        sum += expf(sc[lane][n] * scale - mx);
    float s2 = 0.f;
    for (int n = 0; n < N_MEM; ++n) {
        const float e = expf(sc[lane][n] * scale - mx);   // same bits as pass 2
        const float w = e / sum;
        const float d = w - LAM_F;
        s2 += (d > 0.f ? d : 0.f) * w / (fabsf(d) + EPS_F);
    }
    const float s2c = fmaxf(s2, EPS_F);

    // ---- all waves done reading scores; overwrite sc with w_hat ----
    __syncthreads();

    // own stripe: recompute wh from registers (same bits), emit to HBM + LDS
    float* wout = What + (size_t)rowg * N_MEM + wsu * SW;
#pragma unroll
    for (int j = 0; j < SW; ++j) {
        const float e = expf(acc[j] * scale - mx);
        const float w = e / sum;
        const float d = w - LAM_F;
        const float wh = (d > 0.f ? d : 0.f) * w / (fabsf(d) + EPS_F);
        const float whn = wh / s2c;
        wout[j] = whn;                           // output w_hat_spatial
        sc[lane][wsu * SW + j] = whn;            // recon operand (same bits)
    }

    // ---- reconstruction: Fhat[b][c][hw] = sum_n wh[row][n]*m[n][c] ----
    float* Fo = Fhat + plane;
    const int c0w = wsu * (C_DIM / NS);          // 192-wide c-stripe

    for (int cb = 0; cb < C_DIM / NS; cb += CB_R) {
        __syncthreads();                         // wh visible / prior chunk consumed
        {   // stage 4 c-regions x CB_R c's x 112 floats = 896 float4
            float4* dst4 = reinterpret_cast<float4*>(mbuf);
            for (int i = tid; i < NS * CB_R * CROW / 4; i += 256) {
                const int s   = i / (CB_R * CROW / 4);
                const int rem = i % (CB_R * CROW / 4);
                const float4* src4 = reinterpret_cast<const float4*>(
                    mTp + (size_t)(s * (C_DIM / NS) + cb) * CROW);
                dst4[i] = src4[rem];
            }
        }
        __syncthreads();

        f32x2 v2[CB_R];                          // even/odd-j partial chains
        float vs[CB_R];                          // j=24 chain
#pragma unroll
        for (int t = 0; t < CB_R; ++t) { v2[t] = f32x2{0.f, 0.f}; vs[t] = 0.f; }

#pragma unroll
        for (int nc = 0; nc < NS; ++nc) {
            f32x2 wr2[12];
#pragma unroll
            for (int p = 0; p < 12; ++p)
                wr2[p] = f32x2{sc[lane][nc * SW + 2 * p],
                               sc[lane][nc * SW + 2 * p + 1]};   // 2-way max
            const float wr24 = sc[lane][nc * SW + 24];
#pragma unroll
            for (int t = 0; t < CB_R; ++t) {
                const float* mch = mbuf + (wsu * CB_R + t) * CROW + nc * SWP;
                const f32x4* mch4 = reinterpret_cast<const f32x4*>(mch);  // broadcast
#pragma unroll
                for (int q = 0; q < 6; ++q) {
                    const f32x4 m4 = mch4[q];
                    const f32x2 mlo = __builtin_shufflevector(m4, m4, 0, 1);
                    const f32x2 mhi = __builtin_shufflevector(m4, m4, 2, 3);
                    v2[t] = __builtin_elementwise_fma(wr2[2 * q], mlo, v2[t]);
                    v2[t] = __builtin_elementwise_fma(wr2[2 * q + 1], mhi, v2[t]);
                }
                vs[t] = fmaf(wr24, mch[24], vs[t]);
            }
        }
#pragma unroll
        for (int t = 0; t < CB_R; ++t)
            Fo[(size_t)(c0w + cb + t) * HW_SZ] = (v2[t].x + v2[t].y) + vs[t];
    }
}

// -------------------------------------------------------------------------
extern "C" void kernel_launch(void* const* d_in, const int* in_sizes, int n_in,
                              void* d_out, int out_size, void* d_ws, size_t ws_size,
                              hipStream_t stream) {
    const float* F   = (const float*)d_in[0];   // [64,768,48,48]
    const float* mem = (const float*)d_in[1];   // [100,768]
    float* Fhat = (float*)d_out;                               // 113,246,208 floats
    float* What = (float*)d_out + (size_t)64 * 768 * 48 * 48;  // 14,745,600 floats
    float* mTp  = (float*)d_ws;                                // 768*112 floats

    prep_mT<<<N_MEM, 64, 0, stream>>>(mem, mTp);
    memmod_fused<<<2304, 256, 0, stream>>>(F, mTp, Fhat, What);
}